// Round 6
// baseline (247.278 us; speedup 1.0000x reference)
//
#include <hip/hip_runtime.h>
#include <math.h>

// Problem constants (fixed by reference file)
#define NB   2
#define LQ   16384
#define CDIM 256
#define MH   8          // heads
#define DH   32         // head dim
#define LIN  21760      // 128^2+64^2+32^2+16^2
#define NPIX (NB * LIN) // 43520 total pixels across batch

typedef __attribute__((ext_vector_type(8))) _Float16 f16x8;
typedef __attribute__((ext_vector_type(4))) _Float16 f16x4;
typedef __attribute__((ext_vector_type(4))) float    f32x4;

// async 16B global->LDS (wave-uniform LDS base + lane*16 — no padding allowed)
__device__ __forceinline__ void async16(const void* g, void* l) {
    __builtin_amdgcn_global_load_lds(
        (const __attribute__((address_space(1))) void*)g,
        (__attribute__((address_space(3))) void*)l,
        16, 0, 0);
}

// XCD-aware block swizzle (T1). Requires nwg % 8 == 0.
__device__ __forceinline__ int xcd_swizzle(int b, int nwg) {
    return (b & 7) * (nwg >> 3) + (b >> 3);
}

// ---------------- merged weight transposes: W[k][n] f32 -> t[n][k] f16 ----------
__global__ __launch_bounds__(256) void tsplit_all_kernel(
    const float* __restrict__ Wv, const float* __restrict__ Wo,
    const float* __restrict__ Wf, const float* __restrict__ Wa,
    _Float16* __restrict__ Wvt, _Float16* __restrict__ Wot, _Float16* __restrict__ Wct)
{
    const int i = blockIdx.x * 256 + threadIdx.x;   // 896*256 exact
    const int r = i >> 8;
    const int kk = i & 255;
    if (r < 256) {
        Wvt[r * 256 + kk] = (_Float16)Wv[kk * 256 + r];
    } else if (r < 512) {
        const int n = r - 256;
        Wot[n * 256 + kk] = (_Float16)Wo[kk * 256 + n];
    } else if (r < 768) {
        const int n = r - 512;
        Wct[n * 256 + kk] = (_Float16)Wf[kk * 256 + n];
    } else {
        const int n = r - 768;
        Wct[(256 + n) * 256 + kk] = (_Float16)Wa[kk * 128 + n];
    }
}

// ================= GEMM v4: streaming, ONE barrier, no B staging =================
// R5 lesson: these GEMMs are memory kernels (compute ~5 µs vs HBM floor ~26 µs);
// the stage->drain->compute phases idle the memory pipe ~50%. v4 structure:
//   - block = 64 A-rows, full N. A (only HBM traffic, read ONCE) -> 32 KB LDS.
//   - B (weights, L2-resident) read per-MFMA directly from global; each wave owns
//     a disjoint nt set -> weights read once per block (~185 MB L2 total ~ 5 µs).
//   - ONE __syncthreads per block; after it an unbroken k-outer/nt-inner
//     MFMA + L2-load stream. 32 KB LDS + ~160 VGPR -> 3 blocks/CU.
// A-LDS XOR swizzle (matched write/read involution): 16B-chunk phys = logical ^
// (row & 7) — without it the 16-lane row-column read is a 16-way bank conflict.
// MFMA mapping inherited verbatim from verified v3 (same k order -> identical bits):
//   mfma(bh, ah): bh row = nt*16+l16, chunk = k*32+quad*8 (global read)
//                 ah row = rg*16+l16 (LDS), C-row = bm+rg*16+l16, C-col = nt*16+quad*4+i

template <int NTW, bool A_F32>
__device__ __forceinline__ void stream_core(
    const void* __restrict__ Araw, const _Float16* __restrict__ Wt,
    int bm, _Float16* Ash, f32x4 (&acc)[NTW][4])
{
    const int tid = threadIdx.x;
    const int wave = tid >> 6, lane = tid & 63;
    const int quad = lane >> 4, l16 = lane & 15;

    // ---- stage A: 64 rows x 256 -> f16 LDS, swizzled chunks ----
    if (A_F32) {
        const float* A = (const float*)Araw;
        float4 r0[8], r1[8];
        #pragma unroll
        for (int j = 0; j < 8; ++j) {            // issue all 16 loads first
            const int s = tid + 256 * j;
            const int row = s >> 5, ch = s & 31;
            const float* src = A + (size_t)(bm + row) * 256 + ch * 8;
            r0[j] = *(const float4*)src;
            r1[j] = *(const float4*)(src + 4);
        }
        #pragma unroll
        for (int j = 0; j < 8; ++j) {
            const int s = tid + 256 * j;
            const int row = s >> 5, ch = s & 31;
            f16x8 h;
            h[0] = (_Float16)r0[j].x; h[1] = (_Float16)r0[j].y;
            h[2] = (_Float16)r0[j].z; h[3] = (_Float16)r0[j].w;
            h[4] = (_Float16)r1[j].x; h[5] = (_Float16)r1[j].y;
            h[6] = (_Float16)r1[j].z; h[7] = (_Float16)r1[j].w;
            *(f16x8*)&Ash[row * 256 + ((ch ^ (row & 7)) * 8)] = h;
        }
    } else {
        const _Float16* A = (const _Float16*)Araw;
        #pragma unroll
        for (int j = 0; j < 8; ++j) {            // linear LDS dest, inv-swz source
            const int s = tid + 256 * j;
            const int row = s >> 5, ch = s & 31;
            const int cl = ch ^ (row & 7);
            async16(A + (size_t)(bm + row) * 256 + cl * 8, Ash + s * 8);
        }
    }
    __syncthreads();   // the ONLY barrier

    // ---- stream: k outer, nt inner; B-frags straight from L2 ----
    #pragma unroll
    for (int k = 0; k < 8; ++k) {
        f16x8 ah[4];
        #pragma unroll
        for (int rg = 0; rg < 4; ++rg) {
            const int arow = rg * 16 + l16;
            ah[rg] = *(const f16x8*)&Ash[arow * 256 + (((k * 4 + quad) ^ (arow & 7)) * 8)];
        }
        #pragma unroll
        for (int ntw = 0; ntw < NTW; ++ntw) {
            const int nt = ntw * 4 + wave;       // disjoint nt per wave
            const f16x8 bh = *(const f16x8*)&Wt[(size_t)(nt * 16 + l16) * 256 + k * 32 + quad * 8];
            #pragma unroll
            for (int rg = 0; rg < 4; ++rg)
                acc[ntw][rg] = __builtin_amdgcn_mfma_f32_16x16x32_f16(
                    bh, ah[rg], acc[ntw][rg], 0, 0, 0);
        }
    }
}

// epilogue: routed per nt. OUT_MODE: 0 = f32 flat, 2 = f16 head-major (m,pixel,32).
template <int NTW, int OUT_MODE>
__device__ __forceinline__ void stream_epi(
    f32x4 (&acc)[NTW][4], int bm,
    const float* __restrict__ bias0, const float* __restrict__ bias1,
    void* __restrict__ C0, void* __restrict__ C1, int N, int N0)
{
    const int tid = threadIdx.x;
    const int wave = tid >> 6, lane = tid & 63;
    const int quad = lane >> 4, l16 = lane & 15;
    #pragma unroll
    for (int ntw = 0; ntw < NTW; ++ntw) {
        const int nt = ntw * 4 + wave;
        const int col = nt * 16 + quad * 4;      // 4 consecutive cols
        const bool first = col < N0;
        void* Cb        = first ? C0 : C1;
        const float* bb = first ? bias0 : bias1;
        const int ldc   = first ? N0 : (N - N0);
        const int c2    = first ? col : col - N0;
        const float4 bia = *(const float4*)&bb[c2];
        #pragma unroll
        for (int rg = 0; rg < 4; ++rg) {
            const int rr = bm + rg * 16 + l16;
            float4 v;
            v.x = acc[ntw][rg][0] + bia.x;
            v.y = acc[ntw][rg][1] + bia.y;
            v.z = acc[ntw][rg][2] + bia.z;
            v.w = acc[ntw][rg][3] + bia.w;
            if (OUT_MODE == 0) {
                *(float4*)&((float*)Cb)[(size_t)rr * ldc + c2] = v;
            } else {
                f16x4 h;
                h[0] = (_Float16)v.x; h[1] = (_Float16)v.y;
                h[2] = (_Float16)v.z; h[3] = (_Float16)v.w;
                *(f16x4*)&((_Float16*)Cb)[((size_t)(c2 >> 5) * NPIX + rr) * 32 + (c2 & 31)] = h;
            }
        }
    }
}

// ---- merged GEMM1 (value, head-major f16 out) + GEMM2 (off|attn, routed f32 out)
// 64-row blocks: value 680, offattn 512 -> 1192 blocks (1192 % 8 == 0).
__global__ __launch_bounds__(256) void gemm12_v4(
    const float* __restrict__ IF, const float* __restrict__ Q,
    const _Float16* __restrict__ Wvt, const _Float16* __restrict__ Wct,
    const float* __restrict__ b_val, const float* __restrict__ b_off,
    const float* __restrict__ b_attn,
    _Float16* __restrict__ value16, float* __restrict__ offbuf, float* __restrict__ attnbuf)
{
    __shared__ __align__(16) _Float16 Ash[64 * 256];   // 32 KB
    const int wid = xcd_swizzle(blockIdx.x, 1192);
    if (wid < 680) {
        f32x4 acc[4][4] = {};
        stream_core<4, true>(IF, Wvt, wid * 64, Ash, acc);
        stream_epi<4, 2>(acc, wid * 64, b_val, b_val, value16, value16, 256, 256);
    } else {
        f32x4 acc[6][4] = {};
        stream_core<6, true>(Q, Wct, (wid - 680) * 64, Ash, acc);
        stream_epi<6, 0>(acc, (wid - 680) * 64, b_off, b_attn, offbuf, attnbuf, 384, 256);
    }
}

// ---- GEMM3: out = sampled(f16) @ Wot + b_out, f32 flat out. 512 blocks.
__global__ __launch_bounds__(256) void gemm3_v4(
    const _Float16* __restrict__ A, const _Float16* __restrict__ Wot,
    const float* __restrict__ b_out, float* __restrict__ out)
{
    __shared__ __align__(16) _Float16 Ash[64 * 256];   // 32 KB
    const int wid = xcd_swizzle(blockIdx.x, 512);
    f32x4 acc[4][4] = {};
    stream_core<4, false>(A, Wot, wid * 64, Ash, acc);
    stream_epi<4, 0>(acc, wid * 64, b_out, b_out, out, out, 256, 256);
}

// ---------------- sampling v10: 8 queries/block, 16 B/lane gathers ----------------
// (unchanged — verified 60.3-60.9 µs, at the dual L2-line/VALU limit)
__global__ __launch_bounds__(256) void sample_kernel_v10(
    const _Float16* __restrict__ value,  // (MH, NPIX, 32) f16 head-major
    const float* __restrict__ off,       // (N*LQ, 256)
    const float* __restrict__ attn,      // (N*LQ, 128) RAW logits
    _Float16* __restrict__ outv)
{
    __shared__ __align__(16) int4   ivt[128][8];   // 16 KB
    __shared__ __align__(16) float4 wvt[128][8];   // 16 KB

    const int tid = threadIdx.x;
    const int qbase = blockIdx.x * 8;

    #pragma unroll
    for (int j = 0; j < 4; ++j) {
        const int t  = tid + 256 * j;
        const int q  = t >> 7;
        const int m  = (t >> 4) & 7;
        const int pt = t & 15;          // pt = l*4 + p
        const int l  = pt >> 2;
        const int p  = pt & 3;
        const int qi = qbase + q;
        const int lq = qi & (LQ - 1);
        const int n  = qi >> 14;

        const int Hl = 128 >> l;
        const int STARTS[4] = {0, 16384, 20480, 21504};

        const float2 oxy = *(const float2*)&off[(size_t)qi * 256 + m * 32 + pt * 2];

        // fused softmax over the 16 logits of this (q,m) group (16-lane bijection)
        const float logit = attn[(size_t)qi * 128 + m * 16 + p * 4 + l];
        float mx = logit;
        #pragma unroll
        for (int d = 1; d < 16; d <<= 1) mx = fmaxf(mx, __shfl_xor(mx, d, 16));
        const float e = __expf(logit - mx);
        float sm = e;
        #pragma unroll
        for (int d = 1; d < 16; d <<= 1) sm += __shfl_xor(sm, d, 16);
        const float w = e / sm;

        const float refx = ((lq & 127) + 0.5f) * (1.0f / 128.0f);
        const float refy = ((lq >> 7)  + 0.5f) * (1.0f / 128.0f);

        const float x = refx * (float)Hl + oxy.x - 0.5f;
        const float y = refy * (float)Hl + oxy.y - 0.5f;
        const float x0f = floorf(x), y0f = floorf(y);
        const int x0 = (int)x0f, y0 = (int)y0f;
        const int x1 = x0 + 1,  y1 = y0 + 1;
        const float fx = x - x0f, fy = y - y0f;
        const float gx = 1.f - fx, gy = 1.f - fy;

        const float vx0 = (x0 >= 0 && x0 < Hl) ? 1.f : 0.f;
        const float vx1 = (x1 >= 0 && x1 < Hl) ? 1.f : 0.f;
        const float vy0 = (y0 >= 0 && y0 < Hl) ? 1.f : 0.f;
        const float vy1 = (y1 >= 0 && y1 < Hl) ? 1.f : 0.f;

        const int x0c = min(max(x0, 0), Hl - 1);
        const int x1c = min(max(x1, 0), Hl - 1);
        const int y0c = min(max(y0, 0), Hl - 1);
        const int y1c = min(max(y1, 0), Hl - 1);

        // head-major BYTE offsets; pixel stride 64 B
        const int baseb = m * (NPIX * 64) + (n * LIN + STARTS[l]) * 64;
        const int i00 = baseb + (y0c * Hl + x0c) * 64;
        const int i01 = baseb + (y0c * Hl + x1c) * 64;
        const int i10 = baseb + (y1c * Hl + x0c) * 64;
        const int i11 = baseb + (y1c * Hl + x1c) * 64;

        float4 wv;
        wv.x = w * gy * gx * vy0 * vx0;
        wv.y = w * gy * fx * vy0 * vx1;
        wv.z = w * fy * gx * vy1 * vx0;
        wv.w = w * fy * fx * vy1 * vx1;

        const int cc = m ^ (pt & 7);          // XOR col: conflict-free both phases
        int4 iv = {i00, i01, i10, i11};
        ivt[q * 16 + pt][cc] = iv;
        wvt[q * 16 + pt][cc] = wv;
    }
    __syncthreads();

    // ---- Phase 2: f16x8 gathers (16 B/lane) + vector weighted accumulate ----
    const int q  = tid >> 5;
    const int m  = (tid >> 2) & 7;
    const int d8 = tid & 3;
    const int qi = qbase + q;
    const unsigned dd = (unsigned)(d8 * 16);   // byte offset of this lane's 8 ch
    const char* vp = (const char*)value;

    f32x4 accL = {0.f, 0.f, 0.f, 0.f};
    f32x4 accH = {0.f, 0.f, 0.f, 0.f};
    #pragma unroll
    for (int pt = 0; pt < 16; ++pt) {
        const int cc = m ^ (pt & 7);
        const int4  iv = ivt[q * 16 + pt][cc];
        const float4 wv = wvt[q * 16 + pt][cc];
        const f16x8 v00 = *(const f16x8*)(vp + ((unsigned)iv.x + dd));
        const f16x8 v01 = *(const f16x8*)(vp + ((unsigned)iv.y + dd));
        const f16x8 v10 = *(const f16x8*)(vp + ((unsigned)iv.z + dd));
        const f16x8 v11 = *(const f16x8*)(vp + ((unsigned)iv.w + dd));
        f32x4 l00 = {(float)v00[0], (float)v00[1], (float)v00[2], (float)v00[3]};
        f32x4 h00 = {(float)v00[4], (float)v00[5], (float)v00[6], (float)v00[7]};
        f32x4 l01 = {(float)v01[0], (float)v01[1], (float)v01[2], (float)v01[3]};
        f32x4 h01 = {(float)v01[4], (float)v01[5], (float)v01[6], (float)v01[7]};
        f32x4 l10 = {(float)v10[0], (float)v10[1], (float)v10[2], (float)v10[3]};
        f32x4 h10 = {(float)v10[4], (float)v10[5], (float)v10[6], (float)v10[7]};
        f32x4 l11 = {(float)v11[0], (float)v11[1], (float)v11[2], (float)v11[3]};
        f32x4 h11 = {(float)v11[4], (float)v11[5], (float)v11[6], (float)v11[7]};
        accL += wv.x * l00 + wv.y * l01 + wv.z * l10 + wv.w * l11;
        accH += wv.x * h00 + wv.y * h01 + wv.z * h10 + wv.w * h11;
    }

    f16x8 o;
    o[0] = (_Float16)accL[0]; o[1] = (_Float16)accL[1];
    o[2] = (_Float16)accL[2]; o[3] = (_Float16)accL[3];
    o[4] = (_Float16)accH[0]; o[5] = (_Float16)accH[1];
    o[6] = (_Float16)accH[2]; o[7] = (_Float16)accH[3];
    *(f16x8*)&outv[(size_t)qi * 256 + m * 32 + d8 * 8] = o;
}

// ---------------- launch ----------------
extern "C" void kernel_launch(void* const* d_in, const int* in_sizes, int n_in,
                              void* d_out, int out_size, void* d_ws, size_t ws_size,
                              hipStream_t stream)
{
    const float* query         = (const float*)d_in[0];
    const float* input_flatten = (const float*)d_in[2];
    const float* W_off  = (const float*)d_in[5];
    const float* b_off  = (const float*)d_in[6];
    const float* W_attn = (const float*)d_in[7];
    const float* b_attn = (const float*)d_in[8];
    const float* W_val  = (const float*)d_in[9];
    const float* b_val  = (const float*)d_in[10];
    const float* W_out  = (const float*)d_in[11];
    const float* b_out  = (const float*)d_in[12];
    float* out = (float*)d_out;

    char* w = (char*)d_ws;
    _Float16* Sf16 = (_Float16*)w;                     // 16.8 MB, sampler->outGEMM
    _Float16* value16 = (_Float16*)(w + 23068672);     // (8, 43520, 32) f16 (22.3 MB)
    float*    attnbuf = (float*)(w + 67633152);        // 32768x128 f32 raw logits
    _Float16* Wvt = (_Float16*)(w + 84410368);         // [256][256] f16
    _Float16* Wot = Wvt + 65536;                       // [256][256] f16
    _Float16* Wct = Wot + 65536;                       // [384][256] f16 (off|attn)
    float* offbuf = out;   // off staged in d_out, consumed before final GEMM

    dim3 blk(256);

    // weight transforms (one merged launch)
    tsplit_all_kernel<<<896, blk, 0, stream>>>(W_val, W_out, W_off, W_attn, Wvt, Wot, Wct);

    // 1+2) merged streaming GEMMs v4: value (head-major f16) || off|attn (routed)
    gemm12_v4<<<1192, blk, 0, stream>>>(
        input_flatten, query, Wvt, Wct, b_val, b_off, b_attn,
        value16, offbuf, attnbuf);

    // 3) sampling: fused softmax + f16 head-major taps -> f16 sampled
    sample_kernel_v10<<<4096, blk, 0, stream>>>(value16, offbuf, attnbuf, Sf16);

    // 4) out = sampled @ W_out + b_out (streaming GEMM v4)
    gemm3_v4<<<512, blk, 0, stream>>>(Sf16, Wot, b_out, out);
}

// Round 7
// 231.753 us; speedup vs baseline: 1.0670x; 1.0670x over previous
//
#include <hip/hip_runtime.h>
#include <math.h>

// Problem constants (fixed by reference file)
#define NB   2
#define LQ   16384
#define CDIM 256
#define MH   8          // heads
#define DH   32         // head dim
#define LIN  21760      // 128^2+64^2+32^2+16^2
#define NPIX (NB * LIN) // 43520 total pixels across batch

typedef __attribute__((ext_vector_type(8))) _Float16 f16x8;
typedef __attribute__((ext_vector_type(4))) _Float16 f16x4;
typedef __attribute__((ext_vector_type(4))) float    f32x4;

// async 16B global->LDS (wave-uniform LDS base + lane*16 — no padding allowed)
__device__ __forceinline__ void async16(const void* g, void* l) {
    __builtin_amdgcn_global_load_lds(
        (const __attribute__((address_space(1))) void*)g,
        (__attribute__((address_space(3))) void*)l,
        16, 0, 0);
}

// XCD-aware block swizzle (T1). Requires nwg % 8 == 0.
__device__ __forceinline__ int xcd_swizzle(int b, int nwg) {
    return (b & 7) * (nwg >> 3) + (b >> 3);
}

// ---------------- merged weight transposes: W[k][n] f32 -> t[n][k] f16 ----------
__global__ __launch_bounds__(256) void tsplit_all_kernel(
    const float* __restrict__ Wv, const float* __restrict__ Wo,
    const float* __restrict__ Wf, const float* __restrict__ Wa,
    _Float16* __restrict__ Wvt, _Float16* __restrict__ Wot, _Float16* __restrict__ Wct)
{
    const int i = blockIdx.x * 256 + threadIdx.x;   // 896*256 exact
    const int r = i >> 8;
    const int kk = i & 255;
    if (r < 256) {
        Wvt[r * 256 + kk] = (_Float16)Wv[kk * 256 + r];
    } else if (r < 512) {
        const int n = r - 256;
        Wot[n * 256 + kk] = (_Float16)Wo[kk * 256 + n];
    } else if (r < 768) {
        const int n = r - 512;
        Wct[n * 256 + kk] = (_Float16)Wf[kk * 256 + n];
    } else {
        const int n = r - 768;
        Wct[(256 + n) * 256 + kk] = (_Float16)Wa[kk * 128 + n];
    }
}

// ================= GEMM v5: double-buffered BK=64 pipeline (T3-minimum) ==========
// R6 lesson: B per-MFMA from L2 = latency serialization (all pipes idle). R5's v3
// (bulk LDS staging) was right but stage->drain->compute was SERIAL. v5: BK=64,
// dbuf A+B = 64 KB LDS (2 blocks/CU preserved), 4 K-tiles; per step issue
// stage(t+1) BEFORE compute(t), A-write AFTER compute (T14 write-late), ONE
// barrier per step. Staging hides under the 32-MFMA phase.
// Both-sides XOR swizzle (rule #21) on 8x16B-chunk rows:
//   phys16Bchunk = logical ^ (row & 7)  -> all ds access <=2 lanes/bank.
// MFMA operand-swapped (bh, ah), same k-order as v3 -> bit-identical outputs.

// stage B-panel K=64 tile via global_load_lds (linear dest, inv-swizzled source)
__device__ __forceinline__ void stageB64(const _Float16* __restrict__ Bt, int brow0,
                                         int k0, _Float16* Bsh, int tid)
{
    #pragma unroll
    for (int j = 0; j < 4; ++j) {
        const int s = tid + 256 * j;          // 16B slot; 8 per 64-f16 row
        const int row = s >> 3, ch = s & 7;
        const int cl = ch ^ (row & 7);
        async16(Bt + (size_t)(brow0 + row) * 256 + k0 + cl * 8, Bsh + s * 8);
    }
}

// A f32 tile: issue loads (regs) / cvt+swizzled LDS write (split for write-late)
__device__ __forceinline__ void issueA64(const float* __restrict__ A, int bm, int k0,
                                         int tid, float4 (&ar)[8])
{
    #pragma unroll
    for (int j = 0; j < 8; ++j) {
        const int s = tid + 256 * j;          // 4-f32 chunk; 16 per row
        const int row = s >> 4, c4 = s & 15;
        ar[j] = *(const float4*)(A + (size_t)(bm + row) * 256 + k0 + c4 * 4);
    }
}
__device__ __forceinline__ void writeA64(_Float16* Ash, int tid, const float4 (&ar)[8])
{
    #pragma unroll
    for (int j = 0; j < 8; ++j) {
        const int s = tid + 256 * j;
        const int row = s >> 4, c4 = s & 15;
        f16x4 h;
        h[0] = (_Float16)ar[j].x; h[1] = (_Float16)ar[j].y;
        h[2] = (_Float16)ar[j].z; h[3] = (_Float16)ar[j].w;
        // logical 16B chunk = c4>>1 (8 f16), half = c4&1; phys = chunk ^ (row&7)
        *(f16x4*)&Ash[row * 64 + ((c4 >> 1) ^ (row & 7)) * 8 + (c4 & 1) * 4] = h;
    }
}

// 2 k32-steps of MFMA on one BK=64 tile (swizzled reads; operand-swapped)
__device__ __forceinline__ void mfma64(const _Float16* Ash, const _Float16* Bsh,
                                       int wave, int quad, int l16, f32x4 (&acc)[2][8])
{
    #pragma unroll
    for (int kk = 0; kk < 2; ++kk) {
        f16x8 ah[2];
        #pragma unroll
        for (int r = 0; r < 2; ++r) {
            const int arow = wave * 32 + r * 16 + l16;
            ah[r] = *(const f16x8*)&Ash[arow * 64 + (((kk * 4 + quad) ^ (arow & 7)) * 8)];
        }
        #pragma unroll
        for (int half = 0; half < 2; ++half) {
            f16x8 bh[4];
            #pragma unroll
            for (int c = 0; c < 4; ++c) {
                const int brow = half * 64 + c * 16 + l16;
                bh[c] = *(const f16x8*)&Bsh[brow * 64 + (((kk * 4 + quad) ^ (brow & 7)) * 8)];
            }
            #pragma unroll
            for (int r = 0; r < 2; ++r)
                #pragma unroll
                for (int c = 0; c < 4; ++c)
                    acc[r][half * 4 + c] = __builtin_amdgcn_mfma_f32_16x16x32_f16(
                        bh[c], ah[r], acc[r][half * 4 + c], 0, 0, 0);
        }
    }
}

// f32-A pipelined core. Ash/Bsh: [2][128*64] halves passed explicitly (static idx).
__device__ __forceinline__ void core_f32_dbuf(
    const float* __restrict__ A, const _Float16* __restrict__ Bt,
    int bm, int bn, _Float16* Ash0, _Float16* Ash1, _Float16* Bsh0, _Float16* Bsh1,
    f32x4 (&acc)[2][8])
{
    const int tid = threadIdx.x;
    const int wave = tid >> 6, lane = tid & 63;
    const int quad = lane >> 4, l16 = lane & 15;

    {   // prologue: tile 0
        float4 ar[8];
        issueA64(A, bm, 0, tid, ar);
        stageB64(Bt, bn, 0, Bsh0, tid);
        writeA64(Ash0, tid, ar);
    }
    __syncthreads();

    #pragma unroll
    for (int t = 0; t < 4; ++t) {
        _Float16* AshC = (t & 1) ? Ash1 : Ash0;
        _Float16* AshN = (t & 1) ? Ash0 : Ash1;
        _Float16* BshC = (t & 1) ? Bsh1 : Bsh0;
        _Float16* BshN = (t & 1) ? Bsh0 : Bsh1;
        float4 ar[8];
        if (t < 3) {                          // issue next-tile loads FIRST
            issueA64(A, bm, (t + 1) * 64, tid, ar);
            stageB64(Bt, bn, (t + 1) * 64, BshN, tid);
        }
        mfma64(AshC, BshC, wave, quad, l16, acc);   // compute current
        if (t < 3) writeA64(AshN, tid, ar);   // write-late: vmcnt hidden by MFMAs
        __syncthreads();                      // next tile ready (B DMA + A lgkm)
    }
}

// f16-A pipelined core: both operands all-DMA.
__device__ __forceinline__ void core_f16_dbuf(
    const _Float16* __restrict__ A, const _Float16* __restrict__ Bt,
    int bm, int bn, _Float16* Ash0, _Float16* Ash1, _Float16* Bsh0, _Float16* Bsh1,
    f32x4 (&acc)[2][8])
{
    const int tid = threadIdx.x;
    const int wave = tid >> 6, lane = tid & 63;
    const int quad = lane >> 4, l16 = lane & 15;

    stageB64(A, bm, 0, Ash0, tid);            // A staged with same helper (rows=bm)
    stageB64(Bt, bn, 0, Bsh0, tid);
    __syncthreads();

    #pragma unroll
    for (int t = 0; t < 4; ++t) {
        _Float16* AshC = (t & 1) ? Ash1 : Ash0;
        _Float16* AshN = (t & 1) ? Ash0 : Ash1;
        _Float16* BshC = (t & 1) ? Bsh1 : Bsh0;
        _Float16* BshN = (t & 1) ? Bsh0 : Bsh1;
        if (t < 3) {
            stageB64(A, bm, (t + 1) * 64, AshN, tid);
            stageB64(Bt, bn, (t + 1) * 64, BshN, tid);
        }
        mfma64(AshC, BshC, wave, quad, l16, acc);
        __syncthreads();
    }
}

// epilogue: C-row = bm+wave*32+r*16+l16, C-col = bn+cidx*16+quad*4+i
// OUT_MODE: 0 = f32 flat, 2 = f16 head-major (m, pixel, 32ch).
template <int OUT_MODE>
__device__ __forceinline__ void gemm_epilogue(
    f32x4 (&acc)[2][8], int bm, int bn, int wave, int quad, int l16,
    const float* bias0, const float* bias1, void* C0, void* C1, int N, int N0)
{
    void* Cb; const float* bb; int ldc, coff;
    if (bn < N0) { Cb = C0; bb = bias0; ldc = N0;     coff = 0;  }
    else         { Cb = C1; bb = bias1; ldc = N - N0; coff = N0; }
    #pragma unroll
    for (int cidx = 0; cidx < 8; ++cidx) {
        const int col = bn + cidx * 16 + quad * 4 - coff;   // 4 consecutive cols
        const float4 bia = *(const float4*)&bb[col];
        #pragma unroll
        for (int r = 0; r < 2; ++r) {
            const int rr = bm + wave * 32 + r * 16 + l16;
            float4 v;
            v.x = acc[r][cidx][0] + bia.x;
            v.y = acc[r][cidx][1] + bia.y;
            v.z = acc[r][cidx][2] + bia.z;
            v.w = acc[r][cidx][3] + bia.w;
            if (OUT_MODE == 0) {
                *(float4*)&((float*)Cb)[(size_t)rr * ldc + col] = v;
            } else {
                f16x4 h;
                h[0] = (_Float16)v.x; h[1] = (_Float16)v.y;
                h[2] = (_Float16)v.z; h[3] = (_Float16)v.w;
                *(f16x4*)&((_Float16*)Cb)[((size_t)(col >> 5) * NPIX + rr) * 32 + (col & 31)] = h;
            }
        }
    }
}

// ---- merged GEMM1 (value, head-major f16 out) + GEMM2 (off|attn, routed f32 out)
// GEMM1: 680 work-ids (340y x 2x), A=IF f32.  GEMM2: 768 (256y x 3x), A=query f32.
__global__ __launch_bounds__(256) void gemm12_v5(
    const float* __restrict__ IF, const float* __restrict__ Q,
    const _Float16* __restrict__ Wvt, const _Float16* __restrict__ Wct,
    const float* __restrict__ b_val, const float* __restrict__ b_off,
    const float* __restrict__ b_attn,
    _Float16* __restrict__ value16, float* __restrict__ offbuf, float* __restrict__ attnbuf)
{
    __shared__ __align__(16) _Float16 Ash[2][128 * 64];   // 32 KB
    __shared__ __align__(16) _Float16 Bsh[2][128 * 64];   // 32 KB
    f32x4 acc[2][8] = {};
    const int tid = threadIdx.x;
    const int wave = tid >> 6, lane = tid & 63;
    const int quad = lane >> 4, l16 = lane & 15;
    const int wid = xcd_swizzle(blockIdx.x, 1448);        // 1448 % 8 == 0

    if (wid < 680) {
        const int bm = (wid >> 1) * 128, bn = (wid & 1) * 128;
        core_f32_dbuf(IF, Wvt, bm, bn, Ash[0], Ash[1], Bsh[0], Bsh[1], acc);
        gemm_epilogue<2>(acc, bm, bn, wave, quad, l16,
                         b_val, b_val, value16, value16, 256, 256);
    } else {
        const int r = wid - 680;
        const int bm = (r / 3) * 128, bn = (r % 3) * 128;
        core_f32_dbuf(Q, Wct, bm, bn, Ash[0], Ash[1], Bsh[0], Bsh[1], acc);
        gemm_epilogue<0>(acc, bm, bn, wave, quad, l16,
                         b_off, b_attn, offbuf, attnbuf, 384, 256);
    }
}

// ---- GEMM3: out = sampled(f16) @ Wot + b_out, f32 flat out. 512 work-ids.
__global__ __launch_bounds__(256) void gemm3_v5(
    const _Float16* __restrict__ A, const _Float16* __restrict__ Wot,
    const float* __restrict__ b_out, float* __restrict__ out)
{
    __shared__ __align__(16) _Float16 Ash[2][128 * 64];   // 32 KB
    __shared__ __align__(16) _Float16 Bsh[2][128 * 64];   // 32 KB
    f32x4 acc[2][8] = {};
    const int tid = threadIdx.x;
    const int wave = tid >> 6, lane = tid & 63;
    const int quad = lane >> 4, l16 = lane & 15;
    const int wid = xcd_swizzle(blockIdx.x, 512);         // 512 % 8 == 0
    const int bm = (wid >> 1) * 128, bn = (wid & 1) * 128;
    core_f16_dbuf(A, Wot, bm, bn, Ash[0], Ash[1], Bsh[0], Bsh[1], acc);
    gemm_epilogue<0>(acc, bm, bn, wave, quad, l16,
                     b_out, b_out, out, out, 256, 256);
}

// ---------------- sampling v10: 8 queries/block, 16 B/lane gathers ----------------
// (unchanged — verified 60.3-60.9 µs across R4-R6)
__global__ __launch_bounds__(256) void sample_kernel_v10(
    const _Float16* __restrict__ value,  // (MH, NPIX, 32) f16 head-major
    const float* __restrict__ off,       // (N*LQ, 256)
    const float* __restrict__ attn,      // (N*LQ, 128) RAW logits
    _Float16* __restrict__ outv)
{
    __shared__ __align__(16) int4   ivt[128][8];   // 16 KB
    __shared__ __align__(16) float4 wvt[128][8];   // 16 KB

    const int tid = threadIdx.x;
    const int qbase = blockIdx.x * 8;

    #pragma unroll
    for (int j = 0; j < 4; ++j) {
        const int t  = tid + 256 * j;
        const int q  = t >> 7;
        const int m  = (t >> 4) & 7;
        const int pt = t & 15;          // pt = l*4 + p
        const int l  = pt >> 2;
        const int p  = pt & 3;
        const int qi = qbase + q;
        const int lq = qi & (LQ - 1);
        const int n  = qi >> 14;

        const int Hl = 128 >> l;
        const int STARTS[4] = {0, 16384, 20480, 21504};

        const float2 oxy = *(const float2*)&off[(size_t)qi * 256 + m * 32 + pt * 2];

        // fused softmax over the 16 logits of this (q,m) group (16-lane bijection)
        const float logit = attn[(size_t)qi * 128 + m * 16 + p * 4 + l];
        float mx = logit;
        #pragma unroll
        for (int d = 1; d < 16; d <<= 1) mx = fmaxf(mx, __shfl_xor(mx, d, 16));
        const float e = __expf(logit - mx);
        float sm = e;
        #pragma unroll
        for (int d = 1; d < 16; d <<= 1) sm += __shfl_xor(sm, d, 16);
        const float w = e / sm;

        const float refx = ((lq & 127) + 0.5f) * (1.0f / 128.0f);
        const float refy = ((lq >> 7)  + 0.5f) * (1.0f / 128.0f);

        const float x = refx * (float)Hl + oxy.x - 0.5f;
        const float y = refy * (float)Hl + oxy.y - 0.5f;
        const float x0f = floorf(x), y0f = floorf(y);
        const int x0 = (int)x0f, y0 = (int)y0f;
        const int x1 = x0 + 1,  y1 = y0 + 1;
        const float fx = x - x0f, fy = y - y0f;
        const float gx = 1.f - fx, gy = 1.f - fy;

        const float vx0 = (x0 >= 0 && x0 < Hl) ? 1.f : 0.f;
        const float vx1 = (x1 >= 0 && x1 < Hl) ? 1.f : 0.f;
        const float vy0 = (y0 >= 0 && y0 < Hl) ? 1.f : 0.f;
        const float vy1 = (y1 >= 0 && y1 < Hl) ? 1.f : 0.f;

        const int x0c = min(max(x0, 0), Hl - 1);
        const int x1c = min(max(x1, 0), Hl - 1);
        const int y0c = min(max(y0, 0), Hl - 1);
        const int y1c = min(max(y1, 0), Hl - 1);

        // head-major BYTE offsets; pixel stride 64 B
        const int baseb = m * (NPIX * 64) + (n * LIN + STARTS[l]) * 64;
        const int i00 = baseb + (y0c * Hl + x0c) * 64;
        const int i01 = baseb + (y0c * Hl + x1c) * 64;
        const int i10 = baseb + (y1c * Hl + x0c) * 64;
        const int i11 = baseb + (y1c * Hl + x1c) * 64;

        float4 wv;
        wv.x = w * gy * gx * vy0 * vx0;
        wv.y = w * gy * fx * vy0 * vx1;
        wv.z = w * fy * gx * vy1 * vx0;
        wv.w = w * fy * fx * vy1 * vx1;

        const int cc = m ^ (pt & 7);          // XOR col: conflict-free both phases
        int4 iv = {i00, i01, i10, i11};
        ivt[q * 16 + pt][cc] = iv;
        wvt[q * 16 + pt][cc] = wv;
    }
    __syncthreads();

    // ---- Phase 2: f16x8 gathers (16 B/lane) + vector weighted accumulate ----
    const int q  = tid >> 5;
    const int m  = (tid >> 2) & 7;
    const int d8 = tid & 3;
    const int qi = qbase + q;
    const unsigned dd = (unsigned)(d8 * 16);   // byte offset of this lane's 8 ch
    const char* vp = (const char*)value;

    f32x4 accL = {0.f, 0.f, 0.f, 0.f};
    f32x4 accH = {0.f, 0.f, 0.f, 0.f};
    #pragma unroll
    for (int pt = 0; pt < 16; ++pt) {
        const int cc = m ^ (pt & 7);
        const int4  iv = ivt[q * 16 + pt][cc];
        const float4 wv = wvt[q * 16 + pt][cc];
        const f16x8 v00 = *(const f16x8*)(vp + ((unsigned)iv.x + dd));
        const f16x8 v01 = *(const f16x8*)(vp + ((unsigned)iv.y + dd));
        const f16x8 v10 = *(const f16x8*)(vp + ((unsigned)iv.z + dd));
        const f16x8 v11 = *(const f16x8*)(vp + ((unsigned)iv.w + dd));
        f32x4 l00 = {(float)v00[0], (float)v00[1], (float)v00[2], (float)v00[3]};
        f32x4 h00 = {(float)v00[4], (float)v00[5], (float)v00[6], (float)v00[7]};
        f32x4 l01 = {(float)v01[0], (float)v01[1], (float)v01[2], (float)v01[3]};
        f32x4 h01 = {(float)v01[4], (float)v01[5], (float)v01[6], (float)v01[7]};
        f32x4 l10 = {(float)v10[0], (float)v10[1], (float)v10[2], (float)v10[3]};
        f32x4 h10 = {(float)v10[4], (float)v10[5], (float)v10[6], (float)v10[7]};
        f32x4 l11 = {(float)v11[0], (float)v11[1], (float)v11[2], (float)v11[3]};
        f32x4 h11 = {(float)v11[4], (float)v11[5], (float)v11[6], (float)v11[7]};
        accL += wv.x * l00 + wv.y * l01 + wv.z * l10 + wv.w * l11;
        accH += wv.x * h00 + wv.y * h01 + wv.z * h10 + wv.w * h11;
    }

    f16x8 o;
    o[0] = (_Float16)accL[0]; o[1] = (_Float16)accL[1];
    o[2] = (_Float16)accL[2]; o[3] = (_Float16)accL[3];
    o[4] = (_Float16)accH[0]; o[5] = (_Float16)accH[1];
    o[6] = (_Float16)accH[2]; o[7] = (_Float16)accH[3];
    *(f16x8*)&outv[(size_t)qi * 256 + m * 32 + d8 * 8] = o;
}

// ---------------- launch ----------------
extern "C" void kernel_launch(void* const* d_in, const int* in_sizes, int n_in,
                              void* d_out, int out_size, void* d_ws, size_t ws_size,
                              hipStream_t stream)
{
    const float* query         = (const float*)d_in[0];
    const float* input_flatten = (const float*)d_in[2];
    const float* W_off  = (const float*)d_in[5];
    const float* b_off  = (const float*)d_in[6];
    const float* W_attn = (const float*)d_in[7];
    const float* b_attn = (const float*)d_in[8];
    const float* W_val  = (const float*)d_in[9];
    const float* b_val  = (const float*)d_in[10];
    const float* W_out  = (const float*)d_in[11];
    const float* b_out  = (const float*)d_in[12];
    float* out = (float*)d_out;

    char* w = (char*)d_ws;
    _Float16* Sf16 = (_Float16*)w;                     // 16.8 MB, sampler->outGEMM
    _Float16* value16 = (_Float16*)(w + 23068672);     // (8, 43520, 32) f16 (22.3 MB)
    float*    attnbuf = (float*)(w + 67633152);        // 32768x128 f32 raw logits
    _Float16* Wvt = (_Float16*)(w + 84410368);         // [256][256] f16
    _Float16* Wot = Wvt + 65536;                       // [256][256] f16
    _Float16* Wct = Wot + 65536;                       // [384][256] f16 (off|attn)
    float* offbuf = out;   // off staged in d_out, consumed before final GEMM

    dim3 blk(256);

    // weight transforms (one merged launch)
    tsplit_all_kernel<<<896, blk, 0, stream>>>(W_val, W_out, W_off, W_attn, Wvt, Wot, Wct);

    // 1+2) merged dbuf-pipelined GEMMs v5: value (head-major f16) || off|attn (routed)
    gemm12_v5<<<1448, blk, 0, stream>>>(
        input_flatten, query, Wvt, Wct, b_val, b_off, b_attn,
        value16, offbuf, attnbuf);

    // 3) sampling: fused softmax + f16 head-major taps -> f16 sampled
    sample_kernel_v10<<<4096, blk, 0, stream>>>(value16, offbuf, attnbuf, Sf16);

    // 4) out = sampled @ W_out + b_out (dbuf GEMM v5)
    gemm3_v5<<<512, blk, 0, stream>>>(Sf16, Wot, b_out, out);
}